// Round 7
// baseline (894.766 us; speedup 1.0000x reference)
//
#include <hip/hip_runtime.h>
#include <hip/hip_bf16.h>

#define B_ROWS 1024
#define F_FLD  160000
#define D_DIM  16
#define NKB    (F_FLD / 32)        // 5000 K-blocks of 32 cols
#define NSTAT  (D_DIM + 1)         // 16 ev + cacc
#define CCOLS  6400                // cols per chunk
#define NGRP   (CCOLS / 256)       // 25 ballot groups per chunk
#define KBC    (CCOLS / 32)        // 200 K-blocks per chunk
#define NCHUNK (F_FLD / CCOLS)     // 25
#define MSTRIDE 101                // LDS mask row stride (pad: 2-way max = free)

typedef __attribute__((ext_vector_type(8))) short bf16x8;
typedef __attribute__((ext_vector_type(4))) float f32x4;

static __device__ inline unsigned short f2bf(float x) {
    __hip_bfloat16 h = __float2bfloat16(x);
    union { __hip_bfloat16 h; unsigned short s; } u; u.h = h; return u.s;
}

// Expand 8 mask bits -> 8 bf16 (1.0/0.0) in A-fragment register order.
// (verbatim from R4/R5, passing with absmax = bf16 noise)
static __device__ inline bf16x8 expand8(unsigned b) {
    union { unsigned u[4]; bf16x8 v; } r;
    r.u[0] = ((b        & 1u) * 0x3F80u) | (((b >> 1) & 1u) * 0x3F800000u);
    r.u[1] = (((b >> 2) & 1u) * 0x3F80u) | (((b >> 3) & 1u) * 0x3F800000u);
    r.u[2] = (((b >> 4) & 1u) * 0x3F80u) | (((b >> 5) & 1u) * 0x3F800000u);
    r.u[3] = (((b >> 6) & 1u) * 0x3F80u) | (((b >> 7) & 1u) * 0x3F800000u);
    return r.v;
}

// Pack emb -> B-frag bf16 and c -> broadcast-B (verbatim from R5, passing).
__global__ __launch_bounds__(256) void fm_pack(const float* __restrict__ emb,
                                               const float* __restrict__ bias,
                                               unsigned short* __restrict__ embB,
                                               unsigned short* __restrict__ cB2c) {
    const int tid = threadIdx.x;
    const int kb = blockIdx.x * 4 + (tid >> 6);
    const int l = tid & 63, q = l >> 4, n = l & 15;

    float e[8];
    union { unsigned short s[8]; uint4 u; } v;
#pragma unroll
    for (int j = 0; j < 8; ++j) {
        int f = kb * 32 + 4 * j + q;
        e[j] = emb[(size_t)f * D_DIM + n];
        v.s[j] = f2bf(e[j]);
    }
    *(uint4*)(embB + ((size_t)kb * 64 + l) * 8) = v.u;

    union { unsigned short s[8]; uint4 u; } w;
#pragma unroll
    for (int j = 0; j < 8; ++j) {
        float s = e[j] * e[j];
        s += __shfl_xor(s, 1);
        s += __shfl_xor(s, 2);
        s += __shfl_xor(s, 4);
        s += __shfl_xor(s, 8);
        int f = kb * 32 + 4 * j + q;
        w.s[j] = f2bf((n == 0 ? bias[f] : 0.0f) - 0.5f * s);
    }
    if (n == 0) *(uint4*)(cB2c + ((size_t)kb * 4 + q) * 8) = w.u;
}

// PURE STREAM: wave = (row, chunk). Reads 25.6KB sequentially (int4/lane,
// 5-deep prefetch), ballots -> per-lane word selection, one 800B coalesced
// store of 100 mask words. Never leaves the memory phase.
// maskG[(row*25 + ch)*100 + g*4 + q], bit l of word (g,q) <-> col
// ch*6400 + g*256 + 4l + q  (R5-verified convention).
__global__ __launch_bounds__(512, 6) void fm_mask(const int* __restrict__ x,
                                                  unsigned long long* __restrict__ maskG) {
    const int w = threadIdx.x >> 6, l = threadIdx.x & 63;
    const int row = blockIdx.y * 8 + w;
    const int ch  = blockIdx.x;
    const int4* xp = (const int4*)(x + (size_t)row * F_FLD + (size_t)ch * CCOLS) + l;
    const int gt = l >> 1;            // lane's target group (holds words 2l,2l+1)
    const bool odd = l & 1;
    unsigned long long m0 = 0, m1 = 0;

    int4 v[5], u[5];
#pragma unroll
    for (int k = 0; k < 5; ++k) v[k] = xp[k * 64];
    for (int gb = 0; gb < NGRP; gb += 5) {
        const bool more = (gb + 5 < NGRP);
#pragma unroll
        for (int k = 0; k < 5; ++k) u[k] = more ? xp[(size_t)(gb + 5 + k) * 64] : v[k];
#pragma unroll
        for (int k = 0; k < 5; ++k) {
            unsigned long long b0 = __ballot(v[k].x > 0);
            unsigned long long b1 = __ballot(v[k].y > 0);
            unsigned long long b2 = __ballot(v[k].z > 0);
            unsigned long long b3 = __ballot(v[k].w > 0);
            if (gb + k == gt) {       // compiles to cndmask chain
                m0 = odd ? b2 : b0;
                m1 = odd ? b3 : b1;
            }
        }
#pragma unroll
        for (int k = 0; k < 5; ++k) v[k] = u[k];
    }
    if (l < 50) {
        union { unsigned long long m[2]; uint4 u; } st;
        st.m[0] = m0; st.m[1] = m1;
        *(uint4*)(maskG + ((size_t)row * NCHUNK + ch) * 100 + 2 * l) = st.u;
    }
}

// PURE GEMM: block = 64 rows x 1 chunk (6400 cols). Stage masks -> LDS,
// 8 waves = 4 M-subtiles x 2 K-halves, 100 K-steps x 2 MFMAs each,
// LDS-combine K-halves, coalesced plane-major partial write. No atomics.
__global__ __launch_bounds__(512, 4) void fm_gemm(const unsigned long long* __restrict__ maskG,
                                                  const unsigned short* __restrict__ embB,
                                                  const unsigned short* __restrict__ cB2c,
                                                  float* __restrict__ partial) {
    __shared__ unsigned long long mlds[64 * MSTRIDE];   // 51.7 KB
    __shared__ float red[2][4][16][NSTAT];              //  8.7 KB
    const int tid = threadIdx.x;
    const int w = tid >> 6, l = tid & 63;
    const int q = l >> 4, n = l & 15;
    const int ch = blockIdx.x, rowbase = blockIdx.y * 64;
    const int mt = w & 3, kh = w >> 2;

    for (int i = 0; i < 13; ++i) {
        int idx = i * 512 + tid;
        if (idx < 6400) {
            int row = idx / 100, wd = idx - row * 100;
            mlds[row * MSTRIDE + wd] =
                maskG[((size_t)(rowbase + row) * NCHUNK + ch) * 100 + wd];
        }
    }
    __syncthreads();

    f32x4 aev = {0.f, 0.f, 0.f, 0.f}, ac = {0.f, 0.f, 0.f, 0.f};
    const uint4* eB = (const uint4*)embB;
    const uint4* cB = (const uint4*)cB2c;
    const int kbase = ch * KBC + kh * 100;
    const unsigned long long* mrow = mlds + (mt * 16 + n) * MSTRIDE + q;

#pragma unroll 4
    for (int t = 0; t < 100; ++t) {
        int kb_local = kh * 100 + t;
        int g = kb_local >> 3, byt = kb_local & 7;
        unsigned long long mv = mrow[g * 4];
        unsigned b = (unsigned)(mv >> (8 * byt)) & 0xFFu;
        bf16x8 A = expand8(b);
        union { uint4 u; bf16x8 v; } Bf, Cf;
        Bf.u = eB[(size_t)(kbase + t) * 64 + l];
        Cf.u = cB[(size_t)(kbase + t) * 4 + q];
        aev = __builtin_amdgcn_mfma_f32_16x16x32_bf16(A, Bf.v, aev, 0, 0, 0);
        ac  = __builtin_amdgcn_mfma_f32_16x16x32_bf16(A, Cf.v, ac,  0, 0, 0);
    }

    // C/D layout: row = q*4 + r, col = n  (verified)
#pragma unroll
    for (int r = 0; r < 4; ++r) {
        red[kh][mt][q * 4 + r][n] = aev[r];
        if (n == 0) red[kh][mt][q * 4 + r][16] = ac[r];
    }
    __syncthreads();

    // R6 bug fixed: NSTAT*64 = 1088 > 512 threads -> must stride, else
    // planes 8..16 of `partial` keep their 0xAA poison (absmax 1520).
    for (int idx = tid; idx < NSTAT * 64; idx += 512) {
        int col = idx >> 6, row64 = idx & 63;   // consecutive idx -> consecutive rows
        float s = red[0][row64 >> 4][row64 & 15][col]
                + red[1][row64 >> 4][row64 & 15][col];
        partial[((size_t)ch * NSTAT + col) * B_ROWS + rowbase + row64] = s;
    }
}

// Fold 25 chunk-partials (plane-major, fully coalesced):
// out[b] = g_bias + cacc[b] + 0.5 * ||ev[b]||^2
__global__ __launch_bounds__(256) void fm_final(const float* __restrict__ partial,
                                                const float* __restrict__ g_bias,
                                                float* __restrict__ out) {
    int row = blockIdx.x * 256 + threadIdx.x;
    float ev[NSTAT];
#pragma unroll
    for (int d = 0; d < NSTAT; ++d) ev[d] = 0.0f;
    for (int ch = 0; ch < NCHUNK; ++ch) {
        const float* p = partial + (size_t)ch * NSTAT * B_ROWS + row;
#pragma unroll
        for (int d = 0; d < NSTAT; ++d) ev[d] += p[(size_t)d * B_ROWS];
    }
    float s = 0.0f;
#pragma unroll
    for (int d = 0; d < D_DIM; ++d) s += ev[d] * ev[d];
    out[row] = g_bias[0] + ev[16] + 0.5f * s;
}

extern "C" void kernel_launch(void* const* d_in, const int* in_sizes, int n_in,
                              void* d_out, int out_size, void* d_ws, size_t ws_size,
                              hipStream_t stream) {
    const int*   x      = (const int*)d_in[0];
    const float* emb_w  = (const float*)d_in[1];
    const float* bias_w = (const float*)d_in[2];
    const float* g_bias = (const float*)d_in[3];
    float*       out    = (float*)d_out;

    // ws: embB 5,120,000 | cB2c 320,000 | maskG 20,480,000 | partial 1,740,800
    char* p = (char*)d_ws;
    unsigned short*     embB  = (unsigned short*)p;                 p += (size_t)NKB * 64 * 8 * 2;
    unsigned short*     cB2c  = (unsigned short*)p;                 p += (size_t)NKB * 4 * 8 * 2;
    unsigned long long* maskG = (unsigned long long*)p;             p += (size_t)B_ROWS * NCHUNK * 100 * 8;
    float*              partial = (float*)p;

    fm_pack<<<dim3(NKB / 4), dim3(256), 0, stream>>>(emb_w, bias_w, embB, cB2c);
    fm_mask<<<dim3(NCHUNK, B_ROWS / 8), dim3(512), 0, stream>>>(x, maskG);
    fm_gemm<<<dim3(NCHUNK, B_ROWS / 64), dim3(512), 0, stream>>>(maskG, embB, cB2c, partial);
    fm_final<<<dim3(B_ROWS / 256), dim3(256), 0, stream>>>(partial, g_bias, out);
}

// Round 8
// 848.010 us; speedup vs baseline: 1.0551x; 1.0551x over previous
//
#include <hip/hip_runtime.h>
#include <hip/hip_bf16.h>

#define B_ROWS 1024
#define F_FLD  160000
#define D_DIM  16
#define NKB    (F_FLD / 32)        // 5000 K-blocks of 32 cols
#define NSTAT  (D_DIM + 1)         // 16 ev + cacc
#define ACC_N  (B_ROWS * NSTAT)    // 17408
#define CCOLS  6400                // cols per block chunk
#define NGRP   (CCOLS / 256)       // 25 ballot groups per chunk
#define KBC    (CCOLS / 32)        // 200 K-blocks per chunk
#define NCHUNK (F_FLD / CCOLS)     // 25
#define ROWS_B 16                  // rows per block
#define WAVES  8                   // 512 threads

typedef __attribute__((ext_vector_type(8))) short bf16x8;
typedef __attribute__((ext_vector_type(4))) float f32x4;

static __device__ inline unsigned short f2bf(float x) {
    __hip_bfloat16 h = __float2bfloat16(x);
    union { __hip_bfloat16 h; unsigned short s; } u; u.h = h; return u.s;
}

// Expand 8 mask bits -> 8 bf16 (1.0/0.0) in A-fragment register order.
// (verbatim from R4/R5, passing with absmax = bf16 noise)
static __device__ inline bf16x8 expand8(unsigned b) {
    union { unsigned u[4]; bf16x8 v; } r;
    r.u[0] = ((b        & 1u) * 0x3F80u) | (((b >> 1) & 1u) * 0x3F800000u);
    r.u[1] = (((b >> 2) & 1u) * 0x3F80u) | (((b >> 3) & 1u) * 0x3F800000u);
    r.u[2] = (((b >> 4) & 1u) * 0x3F80u) | (((b >> 5) & 1u) * 0x3F800000u);
    r.u[3] = (((b >> 6) & 1u) * 0x3F80u) | (((b >> 7) & 1u) * 0x3F800000u);
    return r.v;
}

// Pack emb -> B-frag bf16 (embB[kb][lane][j] = emb[kb*32+4j+q][n], q=lane>>4,
// n=lane&15) and c -> broadcast-B (cB2c[kb][q][j] = bias[f]-0.5||emb[f]||^2,
// f=kb*32+4j+q), computing the row norms in-register via 16-lane butterfly.
// Also zeroes acc (ws is poisoned 0xAA every call).
__global__ __launch_bounds__(256) void fm_pack(const float* __restrict__ emb,
                                               const float* __restrict__ bias,
                                               unsigned short* __restrict__ embB,
                                               unsigned short* __restrict__ cB2c,
                                               float* __restrict__ acc) {
    const int tid = threadIdx.x;
    const int kb = blockIdx.x * 4 + (tid >> 6);
    const int l = tid & 63, q = l >> 4, n = l & 15;

    float e[8];
    union { unsigned short s[8]; uint4 u; } v;
#pragma unroll
    for (int j = 0; j < 8; ++j) {
        int f = kb * 32 + 4 * j + q;
        e[j] = emb[(size_t)f * D_DIM + n];
        v.s[j] = f2bf(e[j]);
    }
    *(uint4*)(embB + ((size_t)kb * 64 + l) * 8) = v.u;

    union { unsigned short s[8]; uint4 u; } w;
#pragma unroll
    for (int j = 0; j < 8; ++j) {
        float s = e[j] * e[j];                    // reduce over n (16 lanes)
        s += __shfl_xor(s, 1);
        s += __shfl_xor(s, 2);
        s += __shfl_xor(s, 4);
        s += __shfl_xor(s, 8);
        int f = kb * 32 + 4 * j + q;
        w.s[j] = f2bf((n == 0 ? bias[f] : 0.0f) - 0.5f * s);
    }
    if (n == 0) *(uint4*)(cB2c + ((size_t)kb * 4 + q) * 8) = w.u;

    int gid = blockIdx.x * 256 + tid;
    if (gid < ACC_N) acc[gid] = 0.0f;
}

// Main: block = 16 rows x 6400 cols. Each wave streams its 2 rows
// SEQUENTIALLY (25 contiguous 1KB wave-loads per row, 5-deep batches) ->
// ballot masks in LDS. One barrier. Waves split 200 K-blocks, 2 MFMAs each
// (ev GEMM + broadcast-c GEMM). LDS tree-reduce 8 partials -> global atomics.
// Measured R5: total 851 us, absmax 8.0 — fm_main ~210 us = ~3.05 TB/s read,
// which matches the device's observed read-stream ceiling (~3.1 TB/s; the
// harness's own x-restore copy reads at the same rate).
__global__ __launch_bounds__(512, 6) void fm_main(const int* __restrict__ x,
                                                  const unsigned short* __restrict__ embB,
                                                  const unsigned short* __restrict__ cB2c,
                                                  float* __restrict__ acc) {
    __shared__ unsigned long long msk[NGRP][ROWS_B][4];   // 12.8 KB
    __shared__ float red[WAVES][ROWS_B][NSTAT];           //  8.7 KB

    const int tid = threadIdx.x;
    const int w = tid >> 6, l = tid & 63;
    const int q = l >> 4, n = l & 15;
    const int rowbase = blockIdx.y * ROWS_B;
    const int c0 = blockIdx.x * CCOLS;

    // ---- stage: wave w -> rows 2w, 2w+1; each row read as one sequential
    // 25.6 KB stream (bit l of word j_w at group g <-> col g*256 + 4l + j_w)
#pragma unroll
    for (int rr = 0; rr < 2; ++rr) {
        const int rloc = 2 * w + rr;
        const int4* xp = (const int4*)(x + (size_t)(rowbase + rloc) * F_FLD + c0) + l;
        for (int g0 = 0; g0 < NGRP; g0 += 5) {
            int4 v[5];
#pragma unroll
            for (int k = 0; k < 5; ++k) v[k] = xp[(size_t)(g0 + k) * 64];
#pragma unroll
            for (int k = 0; k < 5; ++k) {
                unsigned long long m0 = __ballot(v[k].x > 0);
                unsigned long long m1 = __ballot(v[k].y > 0);
                unsigned long long m2 = __ballot(v[k].z > 0);
                unsigned long long m3 = __ballot(v[k].w > 0);
                if (l == 0) {
                    msk[g0 + k][rloc][0] = m0; msk[g0 + k][rloc][1] = m1;
                    msk[g0 + k][rloc][2] = m2; msk[g0 + k][rloc][3] = m3;
                }
            }
        }
    }
    __syncthreads();

    // ---- compute: wave w owns K-blocks w*25 .. w*25+24
    f32x4 aev = {0.f, 0.f, 0.f, 0.f}, ac = {0.f, 0.f, 0.f, 0.f};
    const uint4* eB = (const uint4*)embB;
    const uint4* cB = (const uint4*)cB2c;
    const int kbg0 = blockIdx.x * KBC;

#pragma unroll 2
    for (int t = 0; t < KBC / WAVES; ++t) {
        const int kb = w * (KBC / WAVES) + t;        // 0..199 within chunk
        const int g = kb >> 3, byt = kb & 7;
        // A byte: bits j of byte `byt` of word q, row n  (verified mapping:
        // col kb*32 + 4j + q  ==  bit (byt*8+j) of word q at group g)
        unsigned long long mv = msk[g][n][q];
        unsigned b = (unsigned)(mv >> (8 * byt)) & 0xFFu;
        bf16x8 A = expand8(b);
        union { uint4 u; bf16x8 v; } Bf, Cf;
        Bf.u = eB[(size_t)(kbg0 + kb) * 64 + l];
        Cf.u = cB[(size_t)(kbg0 + kb) * 4 + q];
        aev = __builtin_amdgcn_mfma_f32_16x16x32_bf16(A, Bf.v, aev, 0, 0, 0);
        ac  = __builtin_amdgcn_mfma_f32_16x16x32_bf16(A, Cf.v, ac,  0, 0, 0);
    }

    // ---- reduce 8 wave-partials (C/D layout: row = q*4+r, col = n)
#pragma unroll
    for (int r = 0; r < 4; ++r) {
        red[w][q * 4 + r][n] = aev[r];
        if (n == 0) red[w][q * 4 + r][16] = ac[r];
    }
    __syncthreads();

    if (tid < ROWS_B * NSTAT) {
        int row = tid / NSTAT, col = tid % NSTAT;
        float s = 0.0f;
#pragma unroll
        for (int ww = 0; ww < WAVES; ++ww) s += red[ww][row][col];
        atomicAdd(acc + (size_t)(rowbase + row) * NSTAT + col, s);
    }
}

// out[b] = g_bias + cacc[b] + 0.5 * ||ev[b]||^2
__global__ __launch_bounds__(256) void fm_final(const float* __restrict__ acc,
                                                const float* __restrict__ g_bias,
                                                float* __restrict__ out) {
    int row = blockIdx.x * 256 + threadIdx.x;
    if (row >= B_ROWS) return;
    const float* a = acc + (size_t)row * NSTAT;
    float s = 0.0f;
#pragma unroll
    for (int d = 0; d < D_DIM; ++d) s += a[d] * a[d];
    out[row] = g_bias[0] + a[16] + 0.5f * s;
}

extern "C" void kernel_launch(void* const* d_in, const int* in_sizes, int n_in,
                              void* d_out, int out_size, void* d_ws, size_t ws_size,
                              hipStream_t stream) {
    const int*   x      = (const int*)d_in[0];
    const float* emb_w  = (const float*)d_in[1];
    const float* bias_w = (const float*)d_in[2];
    const float* g_bias = (const float*)d_in[3];
    float*       out    = (float*)d_out;

    // ws: embB 5,120,000 | cB2c 320,000 | acc 69,632
    unsigned short* embB = (unsigned short*)d_ws;
    unsigned short* cB2c = (unsigned short*)((char*)d_ws + (size_t)NKB * 64 * 8 * 2);
    float*          acc  = (float*)((char*)d_ws + (size_t)NKB * 64 * 8 * 2
                                                + (size_t)NKB * 4 * 8 * 2);

    fm_pack<<<dim3(NKB / 4), dim3(256), 0, stream>>>(emb_w, bias_w, embB, cB2c, acc);
    fm_main<<<dim3(NCHUNK, B_ROWS / ROWS_B), dim3(512), 0, stream>>>(x, embB, cB2c, acc);
    fm_final<<<dim3((B_ROWS + 255) / 256), dim3(256), 0, stream>>>(acc, g_bias, out);
}